// Round 5
// baseline (6468.015 us; speedup 1.0000x reference)
//
#include <hip/hip_runtime.h>
#include <math.h>

#define T_STEPS 1024
#define B_SZ    256
#define K_DIM   128
#define IN_DIM  64
#define M_DIM   63
#define NTHREADS 1024
#define ZP_STRIDE 520   // padded zpart row (f32): 520*4B % 128B = 32B -> cb's spread over banks
#define VW_STRIDE 132   // padded leading dim for Vw in LDS (f32)

#define DOT4(acc, W, V) (acc) += (W).x*(V).x + (W).y*(V).y + (W).z*(V).z + (W).w*(V).w

__device__ __forceinline__ float fast_sigmoid(float z) {
    return __builtin_amdgcn_rcpf(1.0f + __expf(-z));
}
__device__ __forceinline__ float fast_tanh(float z) {
    z = fminf(15.0f, fmaxf(-15.0f, z));          // med3 clamp, avoids inf/inf
    float t = __expf(2.0f * z);
    return (t - 1.0f) * __builtin_amdgcn_rcpf(t + 1.0f);
}

__global__ __launch_bounds__(NTHREADS)
void lstm_fused(const float* __restrict__ x,   // [B,T,IN]
                const float* __restrict__ Wi, const float* __restrict__ Ui,
                const float* __restrict__ Wf, const float* __restrict__ Uf,
                const float* __restrict__ Wg, const float* __restrict__ Ug,
                const float* __restrict__ Wo, const float* __restrict__ Uo,
                const float* __restrict__ Vw, const float* __restrict__ Vb,
                float* __restrict__ out)       // [B,T,M]
{
    // act layout: abuf[0..127] = h, abuf[128..191] = x_t   (f4: 0..31 = h, 32..47 = x)
    __shared__ __align__(16) float abuf[192];
    __shared__ __align__(16) float zpart[8][ZP_STRIDE];
    __shared__ __align__(16) float vlds[M_DIM * VW_STRIDE];
    __shared__ __align__(16) float ybuf[64];

    const int b   = blockIdx.x;
    const int tid = threadIdx.x;

    // ---- dot-phase tiling: thread = (rowgroup rg, colblock cb); 4 rows x 24 cols ----
    const int rg = tid >> 3;        // 0..127 -> rows rg*4 .. rg*4+3
    const int cb = tid & 7;         // 0..7   -> concat-f4 idx cb*6 .. cb*6+5 of [U(32 f4)|W(16 f4)]
    const int row0 = rg * 4;        // never crosses a gate boundary (4 | 128)
    const int rr   = row0 & 127;    // row within gate
    const float* Wb; const float* Ub;
    if      (row0 < 128) { Wb = Wi; Ub = Ui; }
    else if (row0 < 256) { Wb = Wf; Ub = Uf; }
    else if (row0 < 384) { Wb = Wg; Ub = Ug; }
    else                 { Wb = Wo; Ub = Uo; }

    float4 wreg[4][6];   // 96 VGPRs
    #pragma unroll
    for (int j = 0; j < 4; ++j) {
        const float4* Wrow = (const float4*)(Wb + (rr + j) * IN_DIM);  // 16 f4
        const float4* Urow = (const float4*)(Ub + (rr + j) * K_DIM);   // 32 f4
        #pragma unroll
        for (int i = 0; i < 6; ++i) {
            int f4 = cb * 6 + i;
            wreg[j][i] = (f4 < 32) ? Urow[f4] : Wrow[f4 - 32];
        }
    }
    // Defeat rematerialization: values become asm-defined -> must stay resident.
    #pragma unroll
    for (int j = 0; j < 4; ++j)
        #pragma unroll
        for (int i = 0; i < 6; ++i)
            asm volatile("" : "+v"(wreg[j][i].x), "+v"(wreg[j][i].y),
                             "+v"(wreg[j][i].z), "+v"(wreg[j][i].w));

    // ---- Vw into LDS (padded stride) ----
    for (int idx = tid; idx < M_DIM * K_DIM; idx += NTHREADS) {
        int m = idx >> 7;
        int k = idx & 127;
        vlds[m * VW_STRIDE + k] = Vw[idx];
    }

    const size_t xbase = (size_t)b * T_STEPS * IN_DIM;
    const size_t obase = (size_t)b * T_STEPS * M_DIM;

    // ---- init: h = 0, stage x_0 ----
    if (tid < K_DIM) abuf[tid] = 0.0f;
    if (tid >= 128 && tid < 144)
        ((float4*)abuf)[32 + (tid - 128)] = ((const float4*)(x + xbase))[tid - 128];
    float c = 0.0f;

    // y-projection role: threads 512..1015, 8 threads per output column m
    const int r2 = tid - 512;
    const int ym = r2 >> 3;
    const int yj = r2 & 7;
    float vbv = 0.0f;
    if (tid >= 512 && tid < 1016 && yj == 0) vbv = Vb[ym];

    __syncthreads();

    for (int t = 0; t < T_STEPS; ++t) {
        // prefetch x_{t+1} (threads 128..143); written to abuf in phase B
        float4 xpre;
        if (t + 1 < T_STEPS && tid >= 128 && tid < 144)
            xpre = ((const float4*)(x + xbase + (size_t)(t + 1) * IN_DIM))[tid - 128];

        // ---- phase A: 4-row x 24-col partial dot (1 act f4 -> 16 FMAs) ----
        float p0 = 0.f, p1 = 0.f, p2 = 0.f, p3 = 0.f;
        const float4* a4 = (const float4*)abuf;
        #pragma unroll
        for (int i = 0; i < 6; ++i) {
            float4 a = a4[cb * 6 + i];
            DOT4(p0, wreg[0][i], a);
            DOT4(p1, wreg[1][i], a);
            DOT4(p2, wreg[2][i], a);
            DOT4(p3, wreg[3][i], a);
        }
        *((float4*)&zpart[cb][row0]) = make_float4(p0, p1, p2, p3);

        // ---- y_{t-1} = h_{t-1} @ Vw.T + Vb into ybuf (overlaps phase A) ----
        if (t > 0 && tid >= 512 && tid < 1016) {
            const float4* vr = (const float4*)(vlds + ym * VW_STRIDE + yj * 16);
            float p = 0.0f;
            #pragma unroll
            for (int k = 0; k < 4; ++k) {
                float4 v  = vr[k];
                float4 hh = a4[yj * 4 + k];
                DOT4(p, v, hh);
            }
            p += __shfl_xor(p, 1);
            p += __shfl_xor(p, 2);
            p += __shfl_xor(p, 4);
            if (yj == 0) ybuf[ym] = p + vbv;
        }

        __syncthreads();

        // ---- coalesced y store (wave 15, lanes 0..62) ----
        if (t > 0 && tid >= 960 && tid < 960 + M_DIM)
            out[obase + (size_t)(t - 1) * M_DIM + (tid - 960)] = ybuf[tid - 960];

        // ---- phase B: combine partials, gates, state update (threads 0..127) ----
        if (tid < K_DIM) {
            float zi = 0.f, zf = 0.f, zg = 0.f, zo = 0.f;
            #pragma unroll
            for (int q = 0; q < 8; ++q) {
                zi += zpart[q][tid];
                zf += zpart[q][128 + tid];
                zg += zpart[q][256 + tid];
                zo += zpart[q][384 + tid];
            }
            float gi = fast_sigmoid(zi);
            float gf = fast_sigmoid(zf);
            float gg = fast_tanh(zg);
            float go = fast_sigmoid(zo);
            float tc = fast_tanh(c);       // tanh(c_prev)
            abuf[tid] = go * tc;           // h_t = o * tanh(c_prev)  (reference quirk)
            c = gf * c + gi * gg;          // c_t = f*c_prev + i*g
        }
        if (t + 1 < T_STEPS && tid >= 128 && tid < 144)
            ((float4*)abuf)[32 + (tid - 128)] = xpre;
        __syncthreads();
    }

    // ---- final y for t = T-1 ----
    if (tid >= 512 && tid < 1016) {
        const float4* a4 = (const float4*)abuf;
        const float4* vr = (const float4*)(vlds + ym * VW_STRIDE + yj * 16);
        float p = 0.0f;
        #pragma unroll
        for (int k = 0; k < 4; ++k) {
            float4 v  = vr[k];
            float4 hh = a4[yj * 4 + k];
            DOT4(p, v, hh);
        }
        p += __shfl_xor(p, 1);
        p += __shfl_xor(p, 2);
        p += __shfl_xor(p, 4);
        if (yj == 0) ybuf[ym] = p + vbv;
    }
    __syncthreads();
    if (tid >= 960 && tid < 960 + M_DIM)
        out[obase + (size_t)(T_STEPS - 1) * M_DIM + (tid - 960)] = ybuf[tid - 960];
}

extern "C" void kernel_launch(void* const* d_in, const int* in_sizes, int n_in,
                              void* d_out, int out_size, void* d_ws, size_t ws_size,
                              hipStream_t stream) {
    const float* x  = (const float*)d_in[0];
    const float* Wi = (const float*)d_in[1];
    const float* Ui = (const float*)d_in[2];
    const float* Wf = (const float*)d_in[3];
    const float* Uf = (const float*)d_in[4];
    const float* Wg = (const float*)d_in[5];
    const float* Ug = (const float*)d_in[6];
    const float* Wo = (const float*)d_in[7];
    const float* Uo = (const float*)d_in[8];
    const float* Vw = (const float*)d_in[9];
    const float* Vb = (const float*)d_in[10];
    float* out = (float*)d_out;

    lstm_fused<<<dim3(B_SZ), dim3(NTHREADS), 0, stream>>>(
        x, Wi, Ui, Wf, Uf, Wg, Ug, Wo, Uo, Vw, Vb, out);
}

// Round 6
// 919.348 us; speedup vs baseline: 7.0354x; 7.0354x over previous
//
#include <hip/hip_runtime.h>
#include <math.h>

typedef _Float16 h2 __attribute__((ext_vector_type(2)));
typedef unsigned int u32;

#define T_STEPS 1024
#define B_SZ    256
#define K_DIM   128
#define IN_DIM  64
#define M_DIM   63
#define NTH     512
#define ZP_STRIDE 516    // f32 words per zpart row (512 + 4 pad)
#define VW_STRIDE 68     // h2 words per vlds row (64 + 4 pad; keeps 16B align, spreads banks)

__device__ __forceinline__ h2 as_h2(u32 v) { union { u32 u; h2 h; } c; c.u = v; return c.h; }

#if __has_builtin(__builtin_amdgcn_fdot2)
__device__ __forceinline__ float dot2(h2 a, h2 b, float acc) {
    return __builtin_amdgcn_fdot2(a, b, acc, false);
}
#else
__device__ __forceinline__ float dot2(h2 a, h2 b, float acc) {
    return acc + (float)a.x * (float)b.x + (float)a.y * (float)b.y;
}
#endif

__device__ __forceinline__ float fast_sigmoid(float z) {
    return __builtin_amdgcn_rcpf(1.0f + __expf(-z));
}
__device__ __forceinline__ float fast_tanh(float z) {
    z = fminf(15.0f, fmaxf(-15.0f, z));
    float t = __expf(2.0f * z);
    return (t - 1.0f) * __builtin_amdgcn_rcpf(t + 1.0f);
}

__global__ __launch_bounds__(NTH)
void lstm_fused(const float* __restrict__ x,   // [B,T,IN]
                const float* __restrict__ Wi, const float* __restrict__ Ui,
                const float* __restrict__ Wf, const float* __restrict__ Uf,
                const float* __restrict__ Wg, const float* __restrict__ Ug,
                const float* __restrict__ Wo, const float* __restrict__ Uo,
                const float* __restrict__ Vw, const float* __restrict__ Vb,
                float* __restrict__ out)       // [B,T,M]
{
    // hx: packed-f16 activations, double-buffered.
    // half index 0..127 = h, 128..191 = x_t  (h2 word 0..63 = h, 64..95 = x)
    __shared__ __align__(16) h2    hx[2][96];
    __shared__ __align__(16) float zpart[4][ZP_STRIDE];
    __shared__ __align__(16) h2    vlds[M_DIM * VW_STRIDE];

    const int b   = blockIdx.x;
    const int tid = threadIdx.x;

    // dot tiling: thread = (rg, cb) -> rows row0..row0+3, h2-cols cb*24..cb*24+23
    const int rg   = tid >> 2;       // 0..127
    const int cb   = tid & 3;        // 0..3
    const int row0 = rg * 4;         // gate-aligned (4 | 128)
    const int gate = row0 >> 7;
    const int rr   = row0 & 127;
    const float* Ub = (gate == 0) ? Ui : (gate == 1) ? Uf : (gate == 2) ? Ug : Uo;
    const float* Wb = (gate == 0) ? Wi : (gate == 1) ? Wf : (gate == 2) ? Wg : Wo;

    // ---- weights: w[j][i] = f16-pair of cols (2*(cb*24+i), +1) of row rr+j ----
    h2 w[4][24];   // 96 VGPRs
    #pragma unroll
    for (int j = 0; j < 4; ++j) {
        #pragma unroll
        for (int i = 0; i < 24; ++i) {
            int c0 = 2 * (cb * 24 + i);
            const float* s = (c0 < K_DIM) ? (Ub + (rr + j) * K_DIM + c0)
                                          : (Wb + (rr + j) * IN_DIM + (c0 - K_DIM));
            float2 v = *(const float2*)s;
            w[j][i] = h2{(_Float16)v.x, (_Float16)v.y};
        }
    }

    // ---- Vw -> LDS as packed f16 ----
    for (int idx = tid; idx < M_DIM * 64; idx += NTH) {
        int m = idx >> 6, k = idx & 63;
        vlds[m * VW_STRIDE + k] =
            h2{(_Float16)Vw[m * K_DIM + 2 * k], (_Float16)Vw[m * K_DIM + 2 * k + 1]};
    }

    const size_t xbase = (size_t)b * T_STEPS * IN_DIM;
    const size_t obase = (size_t)b * T_STEPS * M_DIM;

    // ---- init: h_{-1} = 0 in hx[0]; x_0 into hx[0] ----
    if (tid < 64) hx[0][tid] = h2{(_Float16)0.f, (_Float16)0.f};
    if (tid >= 128 && tid < 192)
        ((_Float16*)hx[0])[128 + (tid - 128)] = (_Float16)x[xbase + (tid - 128)];
    float c = 0.0f;   // owned by tid<128 (c[tid])

    // y-projection role: threads 256..507, 4 per output column m
    float vbv = 0.0f;
    if (tid >= 256 && tid < 508 && (tid & 3) == 0) vbv = Vb[(tid - 256) >> 2];

    __syncthreads();

    for (int t = 0; t < T_STEPS; ++t) {
        const int par = t & 1;

        // prefetch x_{t+1} (threads 128..191, 1 f32 each, coalesced 256B)
        float xv = 0.0f;
        if (t + 1 < T_STEPS && tid >= 128 && tid < 192)
            xv = x[xbase + (size_t)(t + 1) * IN_DIM + (tid - 128)];

        // ---- phase A: 4-row x 48-col dot, f16 pairs, f32 accumulate ----
        float p0 = 0.f, p1 = 0.f, p2 = 0.f, p3 = 0.f;
        const uint4* A = (const uint4*)(&hx[par][cb * 24]);
        #pragma unroll
        for (int q = 0; q < 6; ++q) {
            uint4 av = A[q];                       // ds_read_b128, wave-broadcast
            h2 a0 = as_h2(av.x), a1 = as_h2(av.y), a2 = as_h2(av.z), a3 = as_h2(av.w);
            p0 = dot2(w[0][q*4+0], a0, p0); p0 = dot2(w[0][q*4+1], a1, p0);
            p0 = dot2(w[0][q*4+2], a2, p0); p0 = dot2(w[0][q*4+3], a3, p0);
            p1 = dot2(w[1][q*4+0], a0, p1); p1 = dot2(w[1][q*4+1], a1, p1);
            p1 = dot2(w[1][q*4+2], a2, p1); p1 = dot2(w[1][q*4+3], a3, p1);
            p2 = dot2(w[2][q*4+0], a0, p2); p2 = dot2(w[2][q*4+1], a1, p2);
            p2 = dot2(w[2][q*4+2], a2, p2); p2 = dot2(w[2][q*4+3], a3, p2);
            p3 = dot2(w[3][q*4+0], a0, p3); p3 = dot2(w[3][q*4+1], a1, p3);
            p3 = dot2(w[3][q*4+2], a2, p3); p3 = dot2(w[3][q*4+3], a3, p3);
        }
        *(float4*)&zpart[cb][row0] = make_float4(p0, p1, p2, p3);

        __syncthreads();   // zpart ready; hx[par] stable for readers below

        if (tid < 128) {
            // ---- gates + state update; c[tid] in regs ----
            float zi = zpart[0][tid]       + zpart[1][tid]
                     + zpart[2][tid]       + zpart[3][tid];
            float zf = zpart[0][128 + tid] + zpart[1][128 + tid]
                     + zpart[2][128 + tid] + zpart[3][128 + tid];
            float zg = zpart[0][256 + tid] + zpart[1][256 + tid]
                     + zpart[2][256 + tid] + zpart[3][256 + tid];
            float zo = zpart[0][384 + tid] + zpart[1][384 + tid]
                     + zpart[2][384 + tid] + zpart[3][384 + tid];
            float gi = fast_sigmoid(zi);
            float gf = fast_sigmoid(zf);
            float gg = fast_tanh(zg);
            float go = fast_sigmoid(zo);
            float tc = fast_tanh(c);                    // tanh(c_prev)
            float hn = go * tc;                         // h_t = o*tanh(c_prev)  (reference quirk)
            c = gf * c + gi * gg;                       // c_t = f*c_prev + i*g
            ((_Float16*)hx[par ^ 1])[tid] = (_Float16)hn;
        } else if (tid < 192) {
            if (t + 1 < T_STEPS)
                ((_Float16*)hx[par ^ 1])[128 + (tid - 128)] = (_Float16)xv;
        } else if (tid >= 256 && tid < 508 && t > 0) {
            // ---- y_{t-1} = h_{t-1} @ Vw.T + Vb  (reads hx[par], no race) ----
            const int r2 = tid - 256, m = r2 >> 2, yj = r2 & 3;
            const uint4* hv = (const uint4*)(&hx[par][yj * 16]);
            const uint4* vv = (const uint4*)(&vlds[m * VW_STRIDE + yj * 16]);
            float p = 0.f;
            #pragma unroll
            for (int q = 0; q < 4; ++q) {
                uint4 h4v = hv[q];
                uint4 v4v = vv[q];
                p = dot2(as_h2(v4v.x), as_h2(h4v.x), p);
                p = dot2(as_h2(v4v.y), as_h2(h4v.y), p);
                p = dot2(as_h2(v4v.z), as_h2(h4v.z), p);
                p = dot2(as_h2(v4v.w), as_h2(h4v.w), p);
            }
            p += __shfl_xor(p, 1);
            p += __shfl_xor(p, 2);
            if (yj == 0) out[obase + (size_t)(t - 1) * M_DIM + m] = p + vbv;
        }

        __syncthreads();
    }

    // ---- final y for t = T-1 (h_{T-1} lives in hx[0] since T is even) ----
    if (tid >= 256 && tid < 508) {
        const int r2 = tid - 256, m = r2 >> 2, yj = r2 & 3;
        const uint4* hv = (const uint4*)(&hx[0][yj * 16]);
        const uint4* vv = (const uint4*)(&vlds[m * VW_STRIDE + yj * 16]);
        float p = 0.f;
        #pragma unroll
        for (int q = 0; q < 4; ++q) {
            uint4 h4v = hv[q];
            uint4 v4v = vv[q];
            p = dot2(as_h2(v4v.x), as_h2(h4v.x), p);
            p = dot2(as_h2(v4v.y), as_h2(h4v.y), p);
            p = dot2(as_h2(v4v.z), as_h2(h4v.z), p);
            p = dot2(as_h2(v4v.w), as_h2(h4v.w), p);
        }
        p += __shfl_xor(p, 1);
        p += __shfl_xor(p, 2);
        if (yj == 0) out[obase + (size_t)(T_STEPS - 1) * M_DIM + m] = p + vbv;
    }
}

extern "C" void kernel_launch(void* const* d_in, const int* in_sizes, int n_in,
                              void* d_out, int out_size, void* d_ws, size_t ws_size,
                              hipStream_t stream) {
    const float* x  = (const float*)d_in[0];
    const float* Wi = (const float*)d_in[1];
    const float* Ui = (const float*)d_in[2];
    const float* Wf = (const float*)d_in[3];
    const float* Uf = (const float*)d_in[4];
    const float* Wg = (const float*)d_in[5];
    const float* Ug = (const float*)d_in[6];
    const float* Wo = (const float*)d_in[7];
    const float* Uo = (const float*)d_in[8];
    const float* Vw = (const float*)d_in[9];
    const float* Vb = (const float*)d_in[10];
    float* out = (float*)d_out;

    lstm_fused<<<dim3(B_SZ), dim3(NTH), 0, stream>>>(
        x, Wi, Ui, Wf, Uf, Wg, Ug, Wo, Uo, Vw, Vb, out);
}

// Round 7
// 878.781 us; speedup vs baseline: 7.3602x; 1.0462x over previous
//
#include <hip/hip_runtime.h>
#include <math.h>

typedef _Float16 h2 __attribute__((ext_vector_type(2)));
typedef unsigned int u32;

#define T_STEPS 1024
#define B_SZ    256
#define K_DIM   128
#define IN_DIM  64
#define M_DIM   63
#define NTH     512
#define ZP_STRIDE 516    // f32 words per zpart row (512 + 4 pad)

__device__ __forceinline__ h2 as_h2(u32 v) { union { u32 u; h2 h; } c; c.u = v; return c.h; }

#if __has_builtin(__builtin_amdgcn_fdot2)
__device__ __forceinline__ float dot2(h2 a, h2 b, float acc) {
    return __builtin_amdgcn_fdot2(a, b, acc, false);
}
#else
__device__ __forceinline__ float dot2(h2 a, h2 b, float acc) {
    return acc + (float)a.x * (float)b.x + (float)a.y * (float)b.y;
}
#endif

__device__ __forceinline__ float fast_sigmoid(float z) {
    return __builtin_amdgcn_rcpf(1.0f + __expf(-z));
}
__device__ __forceinline__ float fast_tanh(float z) {
    z = fminf(15.0f, fmaxf(-15.0f, z));
    float t = __expf(2.0f * z);
    return (t - 1.0f) * __builtin_amdgcn_rcpf(t + 1.0f);
}

// LDS-only barrier: do NOT drain vmcnt (x prefetch / y store stay in flight).
// All data these barriers protect lives in LDS -> lgkmcnt(0) suffices.
__device__ __forceinline__ void block_sync_lds() {
    asm volatile("s_waitcnt lgkmcnt(0)\n\ts_barrier" ::: "memory");
}

__global__ __launch_bounds__(NTH)
void lstm_fused(const float* __restrict__ x,   // [B,T,IN]
                const float* __restrict__ Wi, const float* __restrict__ Ui,
                const float* __restrict__ Wf, const float* __restrict__ Uf,
                const float* __restrict__ Wg, const float* __restrict__ Ug,
                const float* __restrict__ Wo, const float* __restrict__ Uo,
                const float* __restrict__ Vw, const float* __restrict__ Vb,
                float* __restrict__ out)       // [B,T,M]
{
    // hx: packed-f16 activations, double-buffered.
    // half index 0..127 = h, 128..191 = x_t  (h2 word 0..63 = h, 64..95 = x)
    __shared__ __align__(16) h2    hx[2][96];
    __shared__ __align__(16) float zpart[4][ZP_STRIDE];

    const int b   = blockIdx.x;
    const int tid = threadIdx.x;

    // dot tiling: thread = (rg, cb) -> rows row0..row0+3, h2-cols cb*24..cb*24+23
    const int rg   = tid >> 2;       // 0..127
    const int cb   = tid & 3;        // 0..3
    const int row0 = rg * 4;         // gate-aligned (4 | 128)
    const int gate = row0 >> 7;
    const int rr   = row0 & 127;
    const float* Ub = (gate == 0) ? Ui : (gate == 1) ? Uf : (gate == 2) ? Ug : Uo;
    const float* Wb = (gate == 0) ? Wi : (gate == 1) ? Wf : (gate == 2) ? Wg : Wo;

    // ---- weights: w[j][i] = f16-pair of cols (2*(cb*24+i), +1) of row rr+j ----
    h2 w[4][24];   // 96 VGPRs
    #pragma unroll
    for (int j = 0; j < 4; ++j) {
        #pragma unroll
        for (int i = 0; i < 24; ++i) {
            int c0 = 2 * (cb * 24 + i);
            const float* s = (c0 < K_DIM) ? (Ub + (rr + j) * K_DIM + c0)
                                          : (Wb + (rr + j) * IN_DIM + (c0 - K_DIM));
            float2 v = *(const float2*)s;
            w[j][i] = h2{(_Float16)v.x, (_Float16)v.y};
        }
    }

    // ---- y-projection role: threads 256..507, 4 per output column m ----
    // Vw chunk lives in REGISTERS (fixed per thread): Vw[m, yj*32 .. yj*32+31]
    const int r2 = tid - 256;
    const int ym = r2 >> 2;
    const int yj = r2 & 3;
    const bool is_y = (tid >= 256 && tid < 508);
    h2 vwreg[16];
    float vbv = 0.0f;
    if (is_y) {
        const float* src = Vw + ym * K_DIM + yj * 32;
        #pragma unroll
        for (int i = 0; i < 16; ++i)
            vwreg[i] = h2{(_Float16)src[2 * i], (_Float16)src[2 * i + 1]};
        if (yj == 0) vbv = Vb[ym];
    }

    const size_t xbase = (size_t)b * T_STEPS * IN_DIM;
    const size_t obase = (size_t)b * T_STEPS * M_DIM;

    // ---- init: h_{-1} = 0 in hx[0]; x_0 into hx[0] ----
    if (tid < 64) hx[0][tid] = h2{(_Float16)0.f, (_Float16)0.f};
    if (tid >= 128 && tid < 192)
        ((_Float16*)hx[0])[128 + (tid - 128)] = (_Float16)x[xbase + (tid - 128)];
    float c = 0.0f;   // owned by tid<128 (c[tid])

    __syncthreads();

    for (int t = 0; t < T_STEPS; ++t) {
        const int par = t & 1;

        // prefetch x_{t+1} (threads 128..191, 1 f32 each, coalesced 256B);
        // stays in flight across bar1 (LDS-only barrier), waited only at its use.
        float xv = 0.0f;
        if (t + 1 < T_STEPS && tid >= 128 && tid < 192)
            xv = x[xbase + (size_t)(t + 1) * IN_DIM + (tid - 128)];

        // ---- phase A: 4-row x 48-col dot, f16 pairs, f32 accumulate ----
        float p0 = 0.f, p1 = 0.f, p2 = 0.f, p3 = 0.f;
        const uint4* A = (const uint4*)(&hx[par][cb * 24]);
        #pragma unroll
        for (int q = 0; q < 6; ++q) {
            uint4 av = A[q];                       // ds_read_b128, wave-broadcast
            h2 a0 = as_h2(av.x), a1 = as_h2(av.y), a2 = as_h2(av.z), a3 = as_h2(av.w);
            p0 = dot2(w[0][q*4+0], a0, p0); p0 = dot2(w[0][q*4+1], a1, p0);
            p0 = dot2(w[0][q*4+2], a2, p0); p0 = dot2(w[0][q*4+3], a3, p0);
            p1 = dot2(w[1][q*4+0], a0, p1); p1 = dot2(w[1][q*4+1], a1, p1);
            p1 = dot2(w[1][q*4+2], a2, p1); p1 = dot2(w[1][q*4+3], a3, p1);
            p2 = dot2(w[2][q*4+0], a0, p2); p2 = dot2(w[2][q*4+1], a1, p2);
            p2 = dot2(w[2][q*4+2], a2, p2); p2 = dot2(w[2][q*4+3], a3, p2);
            p3 = dot2(w[3][q*4+0], a0, p3); p3 = dot2(w[3][q*4+1], a1, p3);
            p3 = dot2(w[3][q*4+2], a2, p3); p3 = dot2(w[3][q*4+3], a3, p3);
        }
        *(float4*)&zpart[cb][row0] = make_float4(p0, p1, p2, p3);

        block_sync_lds();   // zpart ready; hx[par] stable for readers below

        if (tid < 128) {
            // ---- gates + state update; c[tid] in regs ----
            float zi = zpart[0][tid]       + zpart[1][tid]
                     + zpart[2][tid]       + zpart[3][tid];
            float zf = zpart[0][128 + tid] + zpart[1][128 + tid]
                     + zpart[2][128 + tid] + zpart[3][128 + tid];
            float zg = zpart[0][256 + tid] + zpart[1][256 + tid]
                     + zpart[2][256 + tid] + zpart[3][256 + tid];
            float zo = zpart[0][384 + tid] + zpart[1][384 + tid]
                     + zpart[2][384 + tid] + zpart[3][384 + tid];
            float gi = fast_sigmoid(zi);
            float gf = fast_sigmoid(zf);
            float gg = fast_tanh(zg);
            float go = fast_sigmoid(zo);
            float tc = fast_tanh(c);                    // tanh(c_prev)
            float hn = go * tc;                         // h_t = o*tanh(c_prev)  (reference quirk)
            c = gf * c + gi * gg;                       // c_t = f*c_prev + i*g
            ((_Float16*)hx[par ^ 1])[tid] = (_Float16)hn;
        } else if (tid < 192) {
            if (t + 1 < T_STEPS)
                ((_Float16*)hx[par ^ 1])[128 + (tid - 128)] = (_Float16)xv;
        } else if (is_y && t > 0) {
            // ---- y_{t-1} = h_{t-1} @ Vw.T + Vb  (reads hx[par], no race) ----
            const uint4* hv = (const uint4*)(&hx[par][yj * 16]);
            float p = 0.f;
            #pragma unroll
            for (int q = 0; q < 4; ++q) {
                uint4 h4v = hv[q];
                p = dot2(vwreg[q*4+0], as_h2(h4v.x), p);
                p = dot2(vwreg[q*4+1], as_h2(h4v.y), p);
                p = dot2(vwreg[q*4+2], as_h2(h4v.z), p);
                p = dot2(vwreg[q*4+3], as_h2(h4v.w), p);
            }
            p += __shfl_xor(p, 1);
            p += __shfl_xor(p, 2);
            if (yj == 0) out[obase + (size_t)(t - 1) * M_DIM + ym] = p + vbv;
        }

        block_sync_lds();
    }

    // ---- final y for t = T-1 (h_{T-1} lives in hx[0] since T is even) ----
    if (is_y) {
        const uint4* hv = (const uint4*)(&hx[0][yj * 16]);
        float p = 0.f;
        #pragma unroll
        for (int q = 0; q < 4; ++q) {
            uint4 h4v = hv[q];
            p = dot2(vwreg[q*4+0], as_h2(h4v.x), p);
            p = dot2(vwreg[q*4+1], as_h2(h4v.y), p);
            p = dot2(vwreg[q*4+2], as_h2(h4v.z), p);
            p = dot2(vwreg[q*4+3], as_h2(h4v.w), p);
        }
        p += __shfl_xor(p, 1);
        p += __shfl_xor(p, 2);
        if (yj == 0) out[obase + (size_t)(T_STEPS - 1) * M_DIM + ym] = p + vbv;
    }
}

extern "C" void kernel_launch(void* const* d_in, const int* in_sizes, int n_in,
                              void* d_out, int out_size, void* d_ws, size_t ws_size,
                              hipStream_t stream) {
    const float* x  = (const float*)d_in[0];
    const float* Wi = (const float*)d_in[1];
    const float* Ui = (const float*)d_in[2];
    const float* Wf = (const float*)d_in[3];
    const float* Uf = (const float*)d_in[4];
    const float* Wg = (const float*)d_in[5];
    const float* Ug = (const float*)d_in[6];
    const float* Wo = (const float*)d_in[7];
    const float* Uo = (const float*)d_in[8];
    const float* Vw = (const float*)d_in[9];
    const float* Vb = (const float*)d_in[10];
    float* out = (float*)d_out;

    lstm_fused<<<dim3(B_SZ), dim3(NTH), 0, stream>>>(
        x, Wi, Ui, Wf, Uf, Wg, Ug, Wo, Uo, Vw, Vb, out);
}